// Round 9
// baseline (960.126 us; speedup 1.0000x reference)
//
#include <hip/hip_runtime.h>
#include <hip/hip_cooperative_groups.h>

namespace cg = cooperative_groups;

typedef __attribute__((ext_vector_type(8))) short short8;
typedef __attribute__((ext_vector_type(4))) float floatx4;
typedef __attribute__((ext_vector_type(4))) int intx4;

static __device__ __forceinline__ unsigned short f2bf(float x) {
    unsigned int u = __float_as_uint(x);
    u += 0x7fffu + ((u >> 16) & 1u);
    return (unsigned short)(u >> 16);
}

// 16-lane butterfly add via DPP (VALU pipe, not DS).
template <int CTRL>
static __device__ __forceinline__ float dpp_add(float x) {
    int v = __builtin_amdgcn_update_dpp(0, __float_as_int(x), CTRL, 0xf, 0xf, true);
    return x + __int_as_float(v);
}

struct MonoP {
    const float* feat; const int* iid; const int* seg; const int* last;
    const float* gamma; const float* beta; const float* Wu; const float* Wv;
    const float* bv; const float* we; const float* Wout;
    float* out;
    int* counts; float* dsum; float* dsumsq; float* rstAcc; float* den;
    float* scale; float* shift; float* cbias;
    unsigned short* wut; float* wvs; float* fv;
    unsigned short* featb;
    float* zeroBase; int zeroQuads;
    int N, B, V, numTiles;
};

// ONE cooperative kernel: zero -> hist -> cvtstats -> affine -> prep -> fv -> main -> out,
// separated by grid.sync(). 256 threads; grid sized for guaranteed co-residency
// (4 blocks/CU: LDS 38.9KB*4 <= 160KB, launch_bounds(256,4) caps regs at 128 --
// the R4/R7/R8-proven no-spill config). LDS is a union reused per phase.
// Purpose: (a) eliminate 7 of 8 dispatches + their serialization bubbles;
// (b) make rocprof's single k_mono row reveal the true total GPU work vs the
// persistent ~250us of "others" no top-5 listing could attribute.
__global__ __launch_bounds__(256, 4) void k_mono(MonoP p) {
    cg::grid_group grid = cg::this_grid();
    __shared__ __align__(16) char smem[38912];
    int tid = threadIdx.x;
    int gtid = blockIdx.x * 256 + tid;
    int gsz = gridDim.x * 256;

    // ---- Z: zero workspace (counts/dsum/dsumsq/rstAcc/den) ----
    {
        floatx4* z = (floatx4*)p.zeroBase;
        floatx4 zz = (floatx4)(0.f);
        for (int i = gtid; i < p.zeroQuads; i += gsz) z[i] = zz;
    }
    grid.sync();

    // ---- H: histogram of iid ----
    for (int n = gtid; n < p.N; n += gsz) atomicAdd(&p.counts[p.iid[n]], 1);
    grid.sync();

    // ---- C: fp32->bf16 convert + count-weighted stats ----
    {
        float* red = (float*)smem;
        int r2 = tid >> 7, d = tid & 127;
        float s = 0.f, qa = 0.f;
        for (int vp = blockIdx.x; vp * 2 < p.V; vp += gridDim.x) {
            int v = vp * 2 + r2;
            if (v >= p.V) continue;
            float f = p.feat[(size_t)v * 128 + d];
            p.featb[(size_t)v * 128 + d] = f2bf(f);
            float c = (float)p.counts[v];
            if (c != 0.f) { s += c * f; qa += c * f * f; }
        }
        red[tid] = s; __syncthreads();
        if (tid < 128) atomicAdd(&p.dsum[d], red[tid] + red[tid + 128]);
        __syncthreads();
        red[tid] = qa; __syncthreads();
        if (tid < 128) atomicAdd(&p.dsumsq[d], red[tid] + red[tid + 128]);
    }
    grid.sync();

    // ---- A: BN affine constants (one block) ----
    if (blockIdx.x == 0 && tid < 128) {
        int d = tid;
        float invN = 1.f / (float)p.N;
        float mean = p.dsum[d] * invN;
        float var  = p.dsumsq[d] * invN - mean * mean;
        float sc   = p.gamma[d] * rsqrtf(var + 1e-5f);
        p.scale[d] = sc;
        p.shift[d] = p.beta[d] - mean * sc;
    }
    grid.sync();

    // ---- P: fold scale into weights; fused bias (blocks 0-63, 2 h per block) ----
    if (blockIdx.x < 64) {
        float (*red)[128] = (float(*)[128])smem;
        int d = tid & 127, half = tid >> 7;
        int h = blockIdx.x * 2 + half;
        float sc = p.scale[d], sh = p.shift[d];
        float wu = p.Wu[d * 128 + h], wvv = p.Wv[d * 128 + h];
        p.wut[h * 128 + d] = f2bf(sc * wu);
        p.wvs[d * 128 + h] = sc * wvv;
        red[half][d] = sh * (wu + wvv);
        __syncthreads();
        for (int off = 64; off > 0; off >>= 1) {
            if (d < off) red[half][d] += red[half][d + off];
            __syncthreads();
        }
        if (d == 0) p.cbias[h] = p.bv[h] + red[half][0];
    }
    grid.sync();

    // ---- F: feat_v per graph (16 graphs per block-job, 2 halves x 8) ----
    {
        float (*sx)[128] = (float(*)[128])smem;
        int h = tid & 127, half = tid >> 7;
        int njob = (p.B + 15) >> 4;
        for (int job = blockIdx.x; job < njob; job += gridDim.x) {
            __syncthreads();        // guard sx reuse
            for (int g = 0; g < 8; ++g) {
                int b = job * 16 + half * 8 + g;
                if (b < p.B) {
                    int row = p.iid[p.last[b]];
                    sx[half * 8 + g][h] = p.feat[(size_t)row * 128 + h];
                }
            }
            __syncthreads();
            float acc[8];
#pragma unroll
            for (int g = 0; g < 8; ++g) acc[g] = 0.f;
            for (int d = 0; d < 128; ++d) {
                float w = p.wvs[d * 128 + h];
#pragma unroll
                for (int g = 0; g < 8; ++g) acc[g] += sx[half * 8 + g][d] * w;
            }
            float cb = p.cbias[h];
            for (int g = 0; g < 8; ++g) {
                int b = job * 16 + half * 8 + g;
                if (b < p.B) p.fv[(size_t)b * 128 + h] = acc[g] + cb;
            }
        }
    }
    grid.sync();

    // ---- M: pipelined e-kernel + fused per-segment weighted sum (R8 body) ----
    if (blockIdx.x < p.numTiles) {
        auto sA   = (unsigned short(*)[64 * 128])(smem);
        auto sSeg = (int(*)[64])(smem + 32768);
        auto sFv  = (float(*)[4][128])(smem + 33280);
        auto sEp  = (float(*)[64])(smem + 37376);

        int wv = tid >> 6, lane = tid & 63, q = lane >> 4, c = lane & 15;
        int p2 = lane & 15;

        short8 bfr[2][4];
        float we2[2];
#pragma unroll
        for (int t = 0; t < 2; ++t) {
            int h = (2 * wv + t) * 16 + c;
            we2[t] = p.we[h];
#pragma unroll
            for (int kc = 0; kc < 4; ++kc)
                bfr[t][kc] = *(const short8*)(p.wut + h * 128 + kc * 32 + q * 8);
        }

        int iidR[4]; int segR; float2 fvR;
        int rowbase = wv * 16 + (lane >> 4);
        auto loadRegs = [&](int T) {
            int n0 = T << 6;
#pragma unroll
            for (int k = 0; k < 4; ++k)
                iidR[k] = p.iid[min(n0 + rowbase + 4 * k, p.N - 1)];
            segR = p.seg[min(n0 + (tid & 63), p.N - 1)];
            int s0 = p.seg[min(n0, p.N - 1)];
            int fvrow = min(s0 + (tid >> 6), p.B - 1);
            fvR = *(const float2*)(p.fv + (size_t)fvrow * 128 + ((tid << 1) & 127));
        };
        auto stage = [&](int buf) {
            unsigned short* sAb = &sA[buf][0];
#pragma unroll
            for (int k = 0; k < 4; ++k) {
                int row = rowbase + 4 * k;
                int j = (p2 & 8) | ((p2 & 7) ^ (row & 7));
                const unsigned short* g = p.featb + (size_t)iidR[k] * 128 + j * 8;
                __builtin_amdgcn_global_load_lds(
                    (const __attribute__((address_space(1))) void*)g,
                    (__attribute__((address_space(3))) void*)(sAb + wv * 2048 + k * 512),
                    16, 0, 0);
            }
            if (tid < 64) sSeg[buf][tid] = segR;
            *(float2*)&sFv[buf][tid >> 6][(tid << 1) & 127] = fvR;
        };

        int T = blockIdx.x;
        loadRegs(T);
        stage(0);
        int cur = 0;

        for (;;) {
            int Tn = T + gridDim.x;
            bool hn = (Tn < p.numTiles);
            if (hn) loadRegs(Tn);
            __syncthreads();            // [1] full drain
            if (hn) stage(cur ^ 1);

            floatx4 acc[4][2];
#pragma unroll
            for (int mt = 0; mt < 4; ++mt)
#pragma unroll
                for (int t = 0; t < 2; ++t) acc[mt][t] = (floatx4)(0.f);
#pragma unroll
            for (int kc = 0; kc < 4; ++kc) {
                int jj = 4 * kc + q;
                int pofs = ((jj & 8) | ((jj & 7) ^ (c & 7))) * 8;
                short8 a0 = *(const short8*)&sA[cur][( 0 + c) * 128 + pofs];
                short8 a1 = *(const short8*)&sA[cur][(16 + c) * 128 + pofs];
                short8 a2 = *(const short8*)&sA[cur][(32 + c) * 128 + pofs];
                short8 a3 = *(const short8*)&sA[cur][(48 + c) * 128 + pofs];
#pragma unroll
                for (int t = 0; t < 2; ++t) {
                    acc[0][t] = __builtin_amdgcn_mfma_f32_16x16x32_bf16(a0, bfr[t][kc], acc[0][t], 0, 0, 0);
                    acc[1][t] = __builtin_amdgcn_mfma_f32_16x16x32_bf16(a1, bfr[t][kc], acc[1][t], 0, 0, 0);
                    acc[2][t] = __builtin_amdgcn_mfma_f32_16x16x32_bf16(a2, bfr[t][kc], acc[2][t], 0, 0, 0);
                    acc[3][t] = __builtin_amdgcn_mfma_f32_16x16x32_bf16(a3, bfr[t][kc], acc[3][t], 0, 0, 0);
                }
            }
            {
                int s0 = sSeg[cur][0];
                int h0 = wv * 32 + c;
#pragma unroll
                for (int mt = 0; mt < 4; ++mt)
#pragma unroll
                    for (int r = 0; r < 4; ++r) {
                        int nl = mt * 16 + q * 4 + r;
                        int sg = sSeg[cur][nl];
                        int off = sg - s0;
                        float f0, f1;
                        if (off < 4) {
                            f0 = sFv[cur][off][h0];
                            f1 = sFv[cur][off][h0 + 16];
                        } else {
                            f0 = p.fv[((size_t)sg << 7) + h0];
                            f1 = p.fv[((size_t)sg << 7) + h0 + 16];
                        }
                        float u0 = acc[mt][0][r] + f0;
                        float u1 = acc[mt][1][r] + f1;
                        float pp = we2[0] * __builtin_amdgcn_rcpf(1.f + __expf(-u0))
                                 + we2[1] * __builtin_amdgcn_rcpf(1.f + __expf(-u1));
                        pp = dpp_add<0xb1>(pp);
                        pp = dpp_add<0x4e>(pp);
                        pp = dpp_add<0x141>(pp);
                        pp = dpp_add<0x140>(pp);
                        if (c == 0) sEp[wv][nl] = pp;
                    }
            }
            // [2] raw barrier: sEp visibility needs lgkmcnt only; keep stage(cur^1)
            // global_load_lds in flight across it (drained at next barrier [1]).
            asm volatile("s_waitcnt lgkmcnt(0)" ::: "memory");
            __builtin_amdgcn_s_barrier();
            __builtin_amdgcn_sched_barrier(0);

            {
                int n0 = T << 6;
                int nb = wv * 16;
                float exr[16];
#pragma unroll
                for (int jg = 0; jg < 4; ++jg) {
                    floatx4 e0 = *(const floatx4*)&sEp[0][nb + jg * 4];
                    floatx4 e1 = *(const floatx4*)&sEp[1][nb + jg * 4];
                    floatx4 e2 = *(const floatx4*)&sEp[2][nb + jg * 4];
                    floatx4 e3 = *(const floatx4*)&sEp[3][nb + jg * 4];
#pragma unroll
                    for (int r = 0; r < 4; ++r) {
                        float s = e0[r] + e1[r] + e2[r] + e3[r];
                        exr[jg * 4 + r] = (n0 + nb + jg * 4 + r < p.N) ? __expf(s) : 0.f;
                    }
                }
                int sgr[16];
#pragma unroll
                for (int jg = 0; jg < 4; ++jg)
                    *(intx4*)&sgr[jg * 4] = *(const intx4*)&sSeg[cur][nb + jg * 4];

                int d0 = lane * 2;
                int jj = lane >> 2;
                int wsub = (lane & 3) * 4;
                const char* base = (const char*)&sA[cur][0];
                float a0 = 0.f, a1 = 0.f, dl = 0.f;
                int curseg = sgr[0];
#pragma unroll
                for (int j = 0; j < 16; ++j) {
                    int row = nb + j;
                    int sg = sgr[j];
                    if (sg != curseg) {
                        atomicAdd(&p.rstAcc[(size_t)curseg * 128 + d0], a0);
                        atomicAdd(&p.rstAcc[(size_t)curseg * 128 + d0 + 1], a1);
                        if (lane == 0) atomicAdd(&p.den[curseg], dl);
                        a0 = a1 = dl = 0.f; curseg = sg;
                    }
                    int ch = (jj & 8) | ((jj & 7) ^ (row & 7));
                    unsigned u = *(const unsigned*)(base + row * 256 + ch * 16 + wsub);
                    float e = exr[j];
                    a0 += e * __uint_as_float(u << 16);
                    a1 += e * __uint_as_float(u & 0xffff0000u);
                    dl += e;
                }
                atomicAdd(&p.rstAcc[(size_t)curseg * 128 + d0], a0);
                atomicAdd(&p.rstAcc[(size_t)curseg * 128 + d0 + 1], a1);
                if (lane == 0) atomicAdd(&p.den[curseg], dl);
            }

            if (!hn) break;
            T = Tn; cur ^= 1;
        }
    }
    grid.sync();

    // ---- O: out = (scale*acc/den) @ W_out + [den>0]*(shift @ W_out) ----
    {
        float (*sT)[36] = (float(*)[36])smem;          // 18432 B
        float* sInv = (float*)(smem + 18432);          // 128 B
        int njob = (p.B + 31) >> 5;
        for (int job = blockIdx.x; job < njob; job += gridDim.x) {
            __syncthreads();        // guard LDS reuse (phase M / prev job)
            int b0 = job * 32;
            int t = tid;
            for (int i = 0; i < 16; ++i) {
                int idx = i * 256 + t;
                int r = idx >> 7, d = idx & 127;
                int b = min(b0 + r, p.B - 1);
                sT[d][r] = p.scale[d] * p.rstAcc[((size_t)b << 7) + d];
            }
            if (t < 32) {
                int b = min(b0 + t, p.B - 1);
                float dn = p.den[b];
                sInv[t] = (dn > 0.f) ? 1.f / dn : 0.f;
            }
            __syncthreads();
            float acc[32];
#pragma unroll
            for (int r = 0; r < 32; ++r) acc[r] = 0.f;
            float sb = 0.f;
            for (int dd = 0; dd < 128; ++dd) {
                float w = p.Wout[dd * 256 + t];
                sb += p.shift[dd] * w;
                const float4* row = (const float4*)&sT[dd][0];
#pragma unroll
                for (int r4 = 0; r4 < 8; ++r4) {
                    float4 v = row[r4];
                    acc[r4 * 4 + 0] += w * v.x;
                    acc[r4 * 4 + 1] += w * v.y;
                    acc[r4 * 4 + 2] += w * v.z;
                    acc[r4 * 4 + 3] += w * v.w;
                }
            }
            for (int r = 0; r < 32; ++r)
                if (b0 + r < p.B) {
                    float inv = sInv[r];
                    p.out[(size_t)(b0 + r) * 256 + t] = acc[r] * inv + (inv != 0.f ? sb : 0.f);
                }
        }
    }
}

extern "C" void kernel_launch(void* const* d_in, const int* in_sizes, int n_in,
                              void* d_out, int out_size, void* d_ws, size_t ws_size,
                              hipStream_t stream) {
    MonoP prm;
    prm.feat  = (const float*)d_in[0];
    prm.iid   = (const int*)d_in[1];
    prm.seg   = (const int*)d_in[2];
    prm.last  = (const int*)d_in[3];
    prm.gamma = (const float*)d_in[4];
    prm.beta  = (const float*)d_in[5];
    prm.Wu    = (const float*)d_in[6];
    prm.Wv    = (const float*)d_in[7];
    prm.bv    = (const float*)d_in[8];
    prm.we    = (const float*)d_in[9];
    prm.Wout  = (const float*)d_in[10];
    prm.out   = (float*)d_out;

    int V = in_sizes[0] / 128;
    int N = in_sizes[1];
    int B = in_sizes[3];

    char* w = (char*)d_ws;
    size_t off = 0;
    auto alloc = [&](size_t bytes) -> void* {
        void* pp = w + off;
        off += (bytes + 255) & ~(size_t)255;
        return pp;
    };
    // zero-init region (contiguous)
    prm.counts = (int*)alloc((size_t)V * 4);
    prm.dsum   = (float*)alloc(512);
    prm.dsumsq = (float*)alloc(512);
    prm.rstAcc = (float*)alloc((size_t)B * 128 * 4);
    prm.den    = (float*)alloc((size_t)B * 4);
    size_t zero_bytes = off;
    // rest
    prm.scale  = (float*)alloc(512);
    prm.shift  = (float*)alloc(512);
    prm.cbias  = (float*)alloc(512);
    prm.wut    = (unsigned short*)alloc(128 * 128 * 2);
    prm.wvs    = (float*)alloc(128 * 128 * 4);
    prm.fv     = (float*)alloc((size_t)B * 128 * 4);
    prm.featb  = (unsigned short*)alloc((size_t)V * 128 * 2);
    (void)ws_size; (void)n_in; (void)out_size;

    prm.zeroBase  = (float*)d_ws;
    prm.zeroQuads = (int)(zero_bytes / 16);
    prm.N = N; prm.B = B; prm.V = V;
    prm.numTiles = (N + 63) / 64;

    // Cooperative grid: guaranteed co-residency. Query occupancy, cap at 4/CU design.
    int maxB = 0;
    hipOccupancyMaxActiveBlocksPerMultiprocessor(&maxB, k_mono, 256, 0);
    if (maxB < 1) maxB = 1;
    int grid = maxB * 256;          // 256 CUs on MI355X
    if (grid > 1024) grid = 1024;

    void* args[] = { (void*)&prm };
    hipLaunchCooperativeKernel((const void*)k_mono, dim3(grid), dim3(256),
                               args, 0, stream);
}

// Round 10
// 490.220 us; speedup vs baseline: 1.9586x; 1.9586x over previous
//
#include <hip/hip_runtime.h>

typedef __attribute__((ext_vector_type(8))) short short8;
typedef __attribute__((ext_vector_type(4))) float floatx4;
typedef __attribute__((ext_vector_type(4))) int intx4;

static __device__ __forceinline__ unsigned short f2bf(float x) {
    unsigned int u = __float_as_uint(x);
    u += 0x7fffu + ((u >> 16) & 1u);
    return (unsigned short)(u >> 16);
}

// 16-lane butterfly add via DPP (VALU pipe, not DS).
template <int CTRL>
static __device__ __forceinline__ float dpp_add(float x) {
    int v = __builtin_amdgcn_update_dpp(0, __float_as_int(x), CTRL, 0xf, 0xf, true);
    return x + __int_as_float(v);
}

// ---------------- K1: histogram of iid ----------------
__global__ void k_hist(const int* __restrict__ iid, int* __restrict__ counts, int N) {
    int n = blockIdx.x * blockDim.x + threadIdx.x;
    if (n < N) atomicAdd(&counts[iid[n]], 1);
}

// ---------------- K2: fp32->bf16 convert + count-weighted stats (one feat pass) ------
__global__ __launch_bounds__(256) void k_cvtstats(const float* __restrict__ feat,
                                                  const int* __restrict__ counts,
                                                  unsigned short* __restrict__ featb,
                                                  float* __restrict__ dsum, float* __restrict__ dsumsq,
                                                  int V) {
    int tid = threadIdx.x;
    int r2 = tid >> 7, d = tid & 127;
    float s = 0.f, qa = 0.f;
    for (int vp = blockIdx.x; vp * 2 < V; vp += gridDim.x) {
        int v = vp * 2 + r2;
        if (v >= V) continue;
        float f = feat[(size_t)v * 128 + d];
        featb[(size_t)v * 128 + d] = f2bf(f);
        float c = (float)counts[v];
        if (c != 0.f) { s += c * f; qa += c * f * f; }
    }
    __shared__ float red[256];
    red[tid] = s; __syncthreads();
    if (tid < 128) atomicAdd(&dsum[d], red[tid] + red[tid + 128]);
    __syncthreads();
    red[tid] = qa; __syncthreads();
    if (tid < 128) atomicAdd(&dsumsq[d], red[tid] + red[tid + 128]);
}

// ---------------- K3: fold scale into weights; fused bias (affine merged in) ----------------
// Each of the 128 blocks redundantly derives scale/shift from the 1KB stats (R4-style);
// block 0 publishes them for k_out. Saves the k_affine dispatch.
__global__ __launch_bounds__(128) void k_prep(const float* __restrict__ Wu, const float* __restrict__ Wv,
                                              const float* __restrict__ bv,
                                              const float* __restrict__ gamma, const float* __restrict__ beta,
                                              const float* __restrict__ dsum, const float* __restrict__ dsumsq,
                                              float invN,
                                              unsigned short* __restrict__ wut, float* __restrict__ wvs,
                                              float* __restrict__ scale, float* __restrict__ shift,
                                              float* __restrict__ cbias) {
    int h = blockIdx.x, d = threadIdx.x;
    float mean = dsum[d] * invN;
    float var  = dsumsq[d] * invN - mean * mean;
    float sc   = gamma[d] * rsqrtf(var + 1e-5f);
    float sh   = beta[d] - mean * sc;
    if (h == 0) { scale[d] = sc; shift[d] = sh; }
    float wu = Wu[d * 128 + h], wv = Wv[d * 128 + h];
    wut[h * 128 + d] = f2bf(sc * wu);
    wvs[d * 128 + h] = sc * wv;
    __shared__ float red[128];
    red[d] = sh * (wu + wv);
    __syncthreads();
    for (int off = 64; off > 0; off >>= 1) {
        if (d < off) red[d] += red[d + off];
        __syncthreads();
    }
    if (d == 0) cbias[h] = bv[h] + red[0];
}

// ---------------- K4: feat_v per graph (+ grid-stride zero of rstAcc/den) ----------------
__global__ __launch_bounds__(128) void k_fv(const float* __restrict__ feat, const int* __restrict__ iid,
                                            const int* __restrict__ last, const float* __restrict__ wvs,
                                            const float* __restrict__ cbias, float* __restrict__ fv,
                                            float* __restrict__ zeroBase, int zeroQuads,
                                            int B) {
    // zero rstAcc+den before k_main (stream order guarantees completion); disjoint
    // from this kernel's other outputs, no extra sync needed.
    {
        int gt = blockIdx.x * 128 + threadIdx.x;
        int gs = gridDim.x * 128;
        floatx4 zz = (floatx4)(0.f);
        floatx4* z = (floatx4*)zeroBase;
        for (int i = gt; i < zeroQuads; i += gs) z[i] = zz;
    }
    const int GPB = 8;
    int b0 = blockIdx.x * GPB;
    int h = threadIdx.x;
    __shared__ float sx[GPB][128];
    for (int g = 0; g < GPB; ++g) {
        int b = b0 + g;
        if (b < B) {
            int row = iid[last[b]];
            sx[g][h] = feat[(size_t)row * 128 + h];
        }
    }
    __syncthreads();
    float acc[GPB];
#pragma unroll
    for (int g = 0; g < GPB; ++g) acc[g] = 0.f;
    for (int d = 0; d < 128; ++d) {
        float w = wvs[d * 128 + h];
#pragma unroll
        for (int g = 0; g < GPB; ++g) acc[g] += sx[g][d] * w;
    }
    float c = cbias[h];
    for (int g = 0; g < GPB; ++g)
        if (b0 + g < B) fv[(size_t)(b0 + g) * 128 + h] = acc[g] + c;
}

// ---------------- K5: pipelined e-kernel + fused per-segment weighted sum ----------------
// R8 structure (best measured), plus exp2-form transcendentals (R4-verified numerics):
// fv pre-scaled by -log2e -> sigmoid input via 1 FMA + exp2; we2 pre-scaled by +log2e
// -> final exp is a bare exp2. Removes ~48 v_mul per wave-tile from the VALU budget.
__global__ __launch_bounds__(256, 4) void k_main(
        const unsigned short* __restrict__ featb, const int* __restrict__ iid,
        const int* __restrict__ seg, const unsigned short* __restrict__ wut,
        const float* __restrict__ fv, const float* __restrict__ we_g,
        float* __restrict__ rstAcc, float* __restrict__ den,
        int N, int B, int numTiles) {
    __shared__ unsigned short sA[2][64 * 128];
    __shared__ int   sSeg[2][64];
    __shared__ float sFv[2][4][128];   // holds -log2e * fv
    __shared__ float sEp[4][64];

    const float NL2E = -1.44269504f;   // -log2(e)
    const float L2E  =  1.44269504f;

    int tid = threadIdx.x;
    int wv = tid >> 6, lane = tid & 63, q = lane >> 4, c = lane & 15;
    int p2 = lane & 15;

    // one-time B fragments: this wave's 32 h-columns (2 h-tiles)
    short8 bfr[2][4];
    float we2[2];
#pragma unroll
    for (int t = 0; t < 2; ++t) {
        int h = (2 * wv + t) * 16 + c;
        we2[t] = we_g[h] * L2E;        // fold log2e into the final exp
#pragma unroll
        for (int kc = 0; kc < 4; ++kc)
            bfr[t][kc] = *(const short8*)(wut + h * 128 + kc * 32 + q * 8);
    }

    if (blockIdx.x >= numTiles) return;

    int iidR[4]; int segR; float2 fvR;
    int rowbase = wv * 16 + (lane >> 4);
    auto loadRegs = [&](int T) {
        int n0 = T << 6;
#pragma unroll
        for (int k = 0; k < 4; ++k)
            iidR[k] = iid[min(n0 + rowbase + 4 * k, N - 1)];
        segR = seg[min(n0 + (tid & 63), N - 1)];
        int s0 = __builtin_amdgcn_readfirstlane(segR);   // lane0 of each wave reads seg[n0]
        int fvrow = min(s0 + (tid >> 6), B - 1);
        fvR = *(const float2*)(fv + (size_t)fvrow * 128 + ((tid << 1) & 127));
        fvR.x *= NL2E; fvR.y *= NL2E;
    };
    auto stage = [&](int buf) {
        unsigned short* sAb = &sA[buf][0];
#pragma unroll
        for (int k = 0; k < 4; ++k) {
            int row = rowbase + 4 * k;
            int j = (p2 & 8) | ((p2 & 7) ^ (row & 7));
            const unsigned short* g = featb + (size_t)iidR[k] * 128 + j * 8;
            __builtin_amdgcn_global_load_lds(
                (const __attribute__((address_space(1))) void*)g,
                (__attribute__((address_space(3))) void*)(sAb + wv * 2048 + k * 512),
                16, 0, 0);
        }
        if (tid < 64) sSeg[buf][tid] = segR;
        *(float2*)&sFv[buf][tid >> 6][(tid << 1) & 127] = fvR;
    };

    int T = blockIdx.x;
    loadRegs(T);
    stage(0);
    int cur = 0;

    for (;;) {
        int Tn = T + gridDim.x;
        bool hn = (Tn < numTiles);
        if (hn) loadRegs(Tn);
        __syncthreads();            // [1] full drain: buf[cur] staged complete; prev phase-2 readers done
        if (hn) stage(cur ^ 1);

        // ---- phase 1: MFMA + partial e for tile T from buf[cur] ----
        floatx4 acc[4][2];
#pragma unroll
        for (int mt = 0; mt < 4; ++mt)
#pragma unroll
            for (int t = 0; t < 2; ++t) acc[mt][t] = (floatx4)(0.f);
#pragma unroll
        for (int kc = 0; kc < 4; ++kc) {
            int jj = 4 * kc + q;
            int pofs = ((jj & 8) | ((jj & 7) ^ (c & 7))) * 8;
            short8 a0 = *(const short8*)&sA[cur][( 0 + c) * 128 + pofs];
            short8 a1 = *(const short8*)&sA[cur][(16 + c) * 128 + pofs];
            short8 a2 = *(const short8*)&sA[cur][(32 + c) * 128 + pofs];
            short8 a3 = *(const short8*)&sA[cur][(48 + c) * 128 + pofs];
#pragma unroll
            for (int t = 0; t < 2; ++t) {
                acc[0][t] = __builtin_amdgcn_mfma_f32_16x16x32_bf16(a0, bfr[t][kc], acc[0][t], 0, 0, 0);
                acc[1][t] = __builtin_amdgcn_mfma_f32_16x16x32_bf16(a1, bfr[t][kc], acc[1][t], 0, 0, 0);
                acc[2][t] = __builtin_amdgcn_mfma_f32_16x16x32_bf16(a2, bfr[t][kc], acc[2][t], 0, 0, 0);
                acc[3][t] = __builtin_amdgcn_mfma_f32_16x16x32_bf16(a3, bfr[t][kc], acc[3][t], 0, 0, 0);
            }
        }
        {
            int s0 = sSeg[cur][0];
            int h0 = wv * 32 + c;
#pragma unroll
            for (int mt = 0; mt < 4; ++mt)
#pragma unroll
                for (int r = 0; r < 4; ++r) {
                    int nl = mt * 16 + q * 4 + r;
                    int sg = sSeg[cur][nl];
                    int off = sg - s0;
                    float f0, f1;
                    if (off < 4) {
                        f0 = sFv[cur][off][h0];
                        f1 = sFv[cur][off][h0 + 16];
                    } else {
                        f0 = NL2E * fv[((size_t)sg << 7) + h0];
                        f1 = NL2E * fv[((size_t)sg << 7) + h0 + 16];
                    }
                    // m = -log2e*u ; sigma(u) = 1/(1 + 2^m)
                    float m0 = __builtin_fmaf(acc[mt][0][r], NL2E, f0);
                    float m1 = __builtin_fmaf(acc[mt][1][r], NL2E, f1);
                    float p = we2[0] * __builtin_amdgcn_rcpf(1.f + __builtin_amdgcn_exp2f(m0))
                            + we2[1] * __builtin_amdgcn_rcpf(1.f + __builtin_amdgcn_exp2f(m1));
                    p = dpp_add<0xb1>(p);
                    p = dpp_add<0x4e>(p);
                    p = dpp_add<0x141>(p);
                    p = dpp_add<0x140>(p);
                    if (c == 0) sEp[wv][nl] = p;
                }
        }
        // [2] raw barrier: sEp visibility needs lgkmcnt only; keep stage(cur^1)
        // global_load_lds in flight across it (drained at next barrier [1]).
        asm volatile("s_waitcnt lgkmcnt(0)" ::: "memory");
        __builtin_amdgcn_s_barrier();
        __builtin_amdgcn_sched_barrier(0);

        // ---- phase 2: fused weighted sum for tile T (16-row strip per wave) ----
        {
            int n0 = T << 6;
            int nb = wv * 16;
            float exr[16];
#pragma unroll
            for (int jg = 0; jg < 4; ++jg) {
                floatx4 e0 = *(const floatx4*)&sEp[0][nb + jg * 4];
                floatx4 e1 = *(const floatx4*)&sEp[1][nb + jg * 4];
                floatx4 e2 = *(const floatx4*)&sEp[2][nb + jg * 4];
                floatx4 e3 = *(const floatx4*)&sEp[3][nb + jg * 4];
#pragma unroll
                for (int r = 0; r < 4; ++r) {
                    float s = e0[r] + e1[r] + e2[r] + e3[r];
                    // sEp already in log2e units -> plain exp2
                    exr[jg * 4 + r] = (n0 + nb + jg * 4 + r < N) ? __builtin_amdgcn_exp2f(s) : 0.f;
                }
            }
            int sgr[16];
#pragma unroll
            for (int jg = 0; jg < 4; ++jg)
                *(intx4*)&sgr[jg * 4] = *(const intx4*)&sSeg[cur][nb + jg * 4];

            int d0 = lane * 2;          // this lane's d-pair
            int jj = lane >> 2;         // 8-ushort chunk index of d0
            int wsub = (lane & 3) * 4;  // byte offset within chunk
            const char* base = (const char*)&sA[cur][0];
            float a0 = 0.f, a1 = 0.f, dl = 0.f;
            int curseg = sgr[0];
#pragma unroll
            for (int j = 0; j < 16; ++j) {
                int row = nb + j;
                int sg = sgr[j];
                if (sg != curseg) {     // wave-uniform branch (sorted segments)
                    atomicAdd(&rstAcc[(size_t)curseg * 128 + d0], a0);
                    atomicAdd(&rstAcc[(size_t)curseg * 128 + d0 + 1], a1);
                    if (lane == 0) atomicAdd(&den[curseg], dl);
                    a0 = a1 = dl = 0.f; curseg = sg;
                }
                int ch = (jj & 8) | ((jj & 7) ^ (row & 7));   // undo stage swizzle
                unsigned u = *(const unsigned*)(base + row * 256 + ch * 16 + wsub);
                float e = exr[j];
                a0 += e * __uint_as_float(u << 16);
                a1 += e * __uint_as_float(u & 0xffff0000u);
                dl += e;
            }
            atomicAdd(&rstAcc[(size_t)curseg * 128 + d0], a0);
            atomicAdd(&rstAcc[(size_t)curseg * 128 + d0 + 1], a1);
            if (lane == 0) atomicAdd(&den[curseg], dl);
        }

        if (!hn) break;
        T = Tn; cur ^= 1;
    }
}

// ---------------- K6: out = (scale*acc/den) @ W_out + [den>0]*(shift @ W_out) ----------------
__global__ __launch_bounds__(256) void k_out(const float* __restrict__ rstAcc,
                                             const float* __restrict__ den,
                                             const float* __restrict__ scale,
                                             const float* __restrict__ shift,
                                             const float* __restrict__ Wout,
                                             float* __restrict__ out, int B) {
    __shared__ float sT[128][36];
    __shared__ float sInv[32];
    int b0 = blockIdx.x * 32;
    int t = threadIdx.x;
    for (int i = 0; i < 16; ++i) {
        int idx = i * 256 + t;
        int r = idx >> 7, d = idx & 127;
        int b = min(b0 + r, B - 1);
        sT[d][r] = scale[d] * rstAcc[((size_t)b << 7) + d];
    }
    if (t < 32) {
        int b = min(b0 + t, B - 1);
        float dn = den[b];
        sInv[t] = (dn > 0.f) ? 1.f / dn : 0.f;
    }
    __syncthreads();
    float acc[32];
#pragma unroll
    for (int r = 0; r < 32; ++r) acc[r] = 0.f;
    float sb = 0.f;
    for (int dd = 0; dd < 128; ++dd) {
        float w = Wout[dd * 256 + t];
        sb += shift[dd] * w;
        const float4* row = (const float4*)&sT[dd][0];
#pragma unroll
        for (int r4 = 0; r4 < 8; ++r4) {
            float4 v = row[r4];
            acc[r4 * 4 + 0] += w * v.x;
            acc[r4 * 4 + 1] += w * v.y;
            acc[r4 * 4 + 2] += w * v.z;
            acc[r4 * 4 + 3] += w * v.w;
        }
    }
    for (int r = 0; r < 32; ++r)
        if (b0 + r < B) {
            float inv = sInv[r];
            out[(size_t)(b0 + r) * 256 + t] = acc[r] * inv + (inv != 0.f ? sb : 0.f);
        }
}

extern "C" void kernel_launch(void* const* d_in, const int* in_sizes, int n_in,
                              void* d_out, int out_size, void* d_ws, size_t ws_size,
                              hipStream_t stream) {
    const float* feat  = (const float*)d_in[0];
    const int*   iid   = (const int*)d_in[1];
    const int*   seg   = (const int*)d_in[2];
    const int*   last  = (const int*)d_in[3];
    const float* gamma = (const float*)d_in[4];
    const float* beta  = (const float*)d_in[5];
    const float* Wu    = (const float*)d_in[6];
    const float* Wv    = (const float*)d_in[7];
    const float* bv    = (const float*)d_in[8];
    const float* we    = (const float*)d_in[9];
    const float* Wout  = (const float*)d_in[10];
    float* out = (float*)d_out;

    int V = in_sizes[0] / 128;
    int N = in_sizes[1];
    int B = in_sizes[3];

    char* w = (char*)d_ws;
    size_t off = 0;
    auto alloc = [&](size_t bytes) -> void* {
        void* p = w + off;
        off += (bytes + 255) & ~(size_t)255;
        return p;
    };
    // memset region (counts + stats only)
    int*   counts = (int*)alloc((size_t)V * 4);
    float* dsum   = (float*)alloc(512);
    float* dsumsq = (float*)alloc(512);
    size_t memset_bytes = off;
    // zeroed-by-k_fv region (contiguous: rstAcc then den)
    size_t zstart = off;
    float* rstAcc = (float*)alloc((size_t)B * 128 * 4);
    float* den    = (float*)alloc((size_t)B * 4);
    size_t zbytes = off - zstart;
    // rest
    float* scale  = (float*)alloc(512);
    float* shift  = (float*)alloc(512);
    float* cbias  = (float*)alloc(512);
    unsigned short* wut = (unsigned short*)alloc(128 * 128 * 2);
    float* wvs    = (float*)alloc(128 * 128 * 4);
    float* fv     = (float*)alloc((size_t)B * 128 * 4);
    unsigned short* featb = (unsigned short*)alloc((size_t)V * 128 * 2);
    (void)ws_size; (void)n_in; (void)out_size;

    hipMemsetAsync(d_ws, 0, memset_bytes, stream);

    k_hist<<<(N + 255) / 256, 256, 0, stream>>>(iid, counts, N);
    k_cvtstats<<<1024, 256, 0, stream>>>(feat, counts, featb, dsum, dsumsq, V);
    k_prep<<<128, 128, 0, stream>>>(Wu, Wv, bv, gamma, beta, dsum, dsumsq,
                                    1.0f / (float)N, wut, wvs, scale, shift, cbias);
    k_fv<<<(B + 7) / 8, 128, 0, stream>>>(feat, iid, last, wvs, cbias, fv,
                                          rstAcc, (int)(zbytes / 16), B);

    int numTiles = (N + 63) / 64;
    k_main<<<1024, 256, 0, stream>>>(featb, iid, seg, wut, fv, we, rstAcc, den, N, B, numTiles);

    k_out<<<(B + 31) / 32, 256, 0, stream>>>(rstAcc, den, scale, shift, Wout, out, B);
}